// Round 4
// baseline (506.181 us; speedup 1.0000x reference)
//
#include <hip/hip_runtime.h>

#define NN 50000
#define NE 800000
#define F  64

typedef __attribute__((ext_vector_type(8))) short bf16x8;
typedef __attribute__((ext_vector_type(4))) float f32x4;

// ---- workspace layout (bytes), 256-aligned ----
#define WS_FLAG   0u
#define WS_WCTH   256u        // 3*128*64 u16: [A|B]^T hi    -> 49408
#define WS_WCTL   49408u      // 3*128*64 u16: [A|B]^T lo    -> 98560
#define WS_W2TH   98560u      // 3*4096 u16 (bf16 hi of W2T) -> 123136
#define WS_W2TL   123136u     // 3*4096 u16 (bf16 lo of W2T) -> 147712
#define WS_SEDGE  147712u     // NE u32 packed (dst<<16)|src -> 3347712
#define WS_U      3347712u    // NN*F f32                    -> 16147712
#define WS_V      16147712u   // NN*F f32                    -> 28947712
// sort scratch aliased inside U region (sort completes before first gemm writes U)
#define WS_BINS   (WS_U + 0u)        // NN int
#define WS_OFFS   (WS_U + 204800u)   // NN int
#define WS_BTOT   (WS_U + 409600u)   // 98 int
#define WS_BTOT2  (WS_U + 410112u)   // 98 int

__device__ __forceinline__ float relu_f(float a) { return a > 0.f ? a : 0.f; }

// --- detect idx payload: int64 (odd words all zero) vs int32 ---
__global__ void detect_kernel(const int* __restrict__ idx, int* __restrict__ flag) {
    int t = blockIdx.x * blockDim.x + threadIdx.x;   // 4096 samples
    if (idx[2 * t + 1] != 0) atomicOr(flag, 1);      // 1 -> int32 layout
}

// --- build transposed hi/lo bf16 splits: WC = [A|B] (A = W1a - W1b, B = W1b), W2T ---
__global__ void prep_kernel(const float* __restrict__ W1, const float* __restrict__ W2,
                            unsigned short* __restrict__ WCTH, unsigned short* __restrict__ WCTL,
                            unsigned short* __restrict__ W2TH, unsigned short* __restrict__ W2TL) {
    int i = blockIdx.x * blockDim.x + threadIdx.x;   // 0 .. 3*4096-1
    int l = i >> 12;
    int r = i & 4095;
    int k = r >> 6;
    int j = r & 63;
    float wa = W1[l * 8192 + k * 64 + j];
    float wb = W1[l * 8192 + 4096 + k * 64 + j];
    float a = wa - wb;
    unsigned ua = __float_as_uint(a), ahi = ua & 0xffff0000u;
    float alo = a - __uint_as_float(ahi);
    WCTH[l * 8192 + j * 64 + k] = (unsigned short)(ahi >> 16);
    WCTL[l * 8192 + j * 64 + k] = (unsigned short)(__float_as_uint(alo) >> 16);
    unsigned ub = __float_as_uint(wb), bhi = ub & 0xffff0000u;
    float blo = wb - __uint_as_float(bhi);
    WCTH[l * 8192 + (64 + j) * 64 + k] = (unsigned short)(bhi >> 16);
    WCTL[l * 8192 + (64 + j) * 64 + k] = (unsigned short)(__float_as_uint(blo) >> 16);
    float w = W2[l * 4096 + k * 64 + j];
    unsigned uw = __float_as_uint(w), whi = uw & 0xffff0000u;
    float wlo = w - __uint_as_float(whi);
    W2TH[l * 4096 + j * 64 + k] = (unsigned short)(whi >> 16);
    W2TL[l * 4096 + j * 64 + k] = (unsigned short)(__float_as_uint(wlo) >> 16);
}

// --- MFMA gemm: [U|V] = x @ [A|B] (+b1 on U). Wave = (64-node batch) x (U or V half).
//     waves_per_eu(2,2): LDS pins occupancy at 2 waves/SIMD anyway; pin the allocator
//     so it budgets the full file instead of spill-chasing unreachable occupancy. ---
__global__ __attribute__((amdgpu_flat_work_group_size(256, 256), amdgpu_waves_per_eu(2, 2)))
void gemm_mfma(
    const float* __restrict__ xin,
    const unsigned short* __restrict__ WCTH, const unsigned short* __restrict__ WCTL,
    const float* __restrict__ b1,
    float* __restrict__ U, float* __restrict__ V) {
    __shared__ char smem[65536];                 // 4 waves x 16 KB, wave-private
    int lane = threadIdx.x & 63;
    int wib  = threadIdx.x >> 6;
    char* base = smem + wib * 16384;
    char* Hhi = base;
    char* Hlo = base + 8192;
    int l15 = lane & 15, l4 = lane >> 4;

    int wid = blockIdx.x * 4 + wib;              // 1564 waves exactly
    int b = wid >> 1;                            // node batch (0..781)
    int half = wid & 1;                          // 0 -> U, 1 -> V

    bf16x8 Bh[2][4], Bl[2][4];
#pragma unroll
    for (int kt = 0; kt < 2; ++kt)
#pragma unroll
        for (int nt = 0; nt < 4; ++nt) {
            int off = (half * 64 + nt * 16 + l15) * 64 + kt * 32 + l4 * 8;
            Bh[kt][nt] = *(const bf16x8*)(WCTH + off);
            Bl[kt][nt] = *(const bf16x8*)(WCTL + off);
        }

    int node = b * 64 + lane;
    int cnode = node < NN ? node : NN - 1;
    const float4* xr = (const float4*)(xin + (size_t)cnode * F);
#pragma unroll
    for (int cc = 0; cc < 8; ++cc) {
        float4 xa = xr[2 * cc], xb = xr[2 * cc + 1];
        float f[8] = {xa.x, xa.y, xa.z, xa.w, xb.x, xb.y, xb.z, xb.w};
        unsigned hi[4], lo[4];
#pragma unroll
        for (int p = 0; p < 4; ++p) {
            float f0 = f[2 * p], f1 = f[2 * p + 1];
            unsigned u0 = __float_as_uint(f0), u1 = __float_as_uint(f1);
            unsigned h0 = u0 & 0xffff0000u, h1 = u1 & 0xffff0000u;
            float l0 = f0 - __uint_as_float(h0);
            float l1 = f1 - __uint_as_float(h1);
            hi[p] = h1 | (h0 >> 16);
            lo[p] = (__float_as_uint(l1) & 0xffff0000u) | (__float_as_uint(l0) >> 16);
        }
        int byt = lane * 128 + ((cc ^ (lane & 7)) << 4);
        *(uint4*)(Hhi + byt) = make_uint4(hi[0], hi[1], hi[2], hi[3]);
        *(uint4*)(Hlo + byt) = make_uint4(lo[0], lo[1], lo[2], lo[3]);
    }

    f32x4 acc[4][4];
#pragma unroll
    for (int mt = 0; mt < 4; ++mt)
#pragma unroll
        for (int nt = 0; nt < 4; ++nt)
            acc[mt][nt] = (f32x4){0.f, 0.f, 0.f, 0.f};
#pragma unroll
    for (int mt = 0; mt < 4; ++mt) {
        int arow = mt * 16 + l15;
        int abase = arow * 128;
        int am = arow & 7;
        bf16x8 Ah0 = *(const bf16x8*)(Hhi + abase + (((0 + l4) ^ am) << 4));
        bf16x8 Ah1 = *(const bf16x8*)(Hhi + abase + (((4 + l4) ^ am) << 4));
        bf16x8 Al0 = *(const bf16x8*)(Hlo + abase + (((0 + l4) ^ am) << 4));
        bf16x8 Al1 = *(const bf16x8*)(Hlo + abase + (((4 + l4) ^ am) << 4));
#pragma unroll
        for (int nt = 0; nt < 4; ++nt) {
            f32x4 a = acc[mt][nt];
            a = __builtin_amdgcn_mfma_f32_16x16x32_bf16(Ah0, Bh[0][nt], a, 0, 0, 0);
            a = __builtin_amdgcn_mfma_f32_16x16x32_bf16(Ah1, Bh[1][nt], a, 0, 0, 0);
            a = __builtin_amdgcn_mfma_f32_16x16x32_bf16(Al0, Bh[0][nt], a, 0, 0, 0);
            a = __builtin_amdgcn_mfma_f32_16x16x32_bf16(Al1, Bh[1][nt], a, 0, 0, 0);
            a = __builtin_amdgcn_mfma_f32_16x16x32_bf16(Ah0, Bl[0][nt], a, 0, 0, 0);
            a = __builtin_amdgcn_mfma_f32_16x16x32_bf16(Ah1, Bl[1][nt], a, 0, 0, 0);
            acc[mt][nt] = a;
        }
    }

    float bc[4];
#pragma unroll
    for (int nt = 0; nt < 4; ++nt)
        bc[nt] = (half == 0) ? b1[nt * 16 + l15] : 0.f;
    float* outp = (half == 0) ? U : V;
#pragma unroll
    for (int mt = 0; mt < 4; ++mt)
#pragma unroll
        for (int nt = 0; nt < 4; ++nt) {
            int col = nt * 16 + l15;
#pragma unroll
            for (int r = 0; r < 4; ++r) {
                int row = b * 64 + mt * 16 + l4 * 4 + r;
                if (row < NN) outp[(size_t)row * F + col] = acc[mt][nt][r] + bc[nt];
            }
        }
}

// --- counting sort by dst ---
__global__ void hist_kernel(const int* __restrict__ idx, const int* __restrict__ flag,
                            int* __restrict__ bins) {
    int e = blockIdx.x * blockDim.x + threadIdx.x;
    int dst = (*flag) ? idx[NE + e] : idx[2 * NE + 2 * e];
    atomicAdd(&bins[dst], 1);
}

__global__ __launch_bounds__(512) void scanA_kernel(const int* __restrict__ bins,
                                                    int* __restrict__ offs,
                                                    int* __restrict__ btot) {
    __shared__ int buf[512];
    int t = threadIdx.x;
    int i = blockIdx.x * 512 + t;
    int v = (i < NN) ? bins[i] : 0;
    buf[t] = v;
    __syncthreads();
    for (int d = 1; d < 512; d <<= 1) {
        int add = (t >= d) ? buf[t - d] : 0;
        __syncthreads();
        buf[t] += add;
        __syncthreads();
    }
    if (i < NN) offs[i] = buf[t] - v;
    if (t == 511) btot[blockIdx.x] = buf[511];
}

__global__ __launch_bounds__(128) void scanB_kernel(const int* __restrict__ btot,
                                                    int* __restrict__ btot2) {
    __shared__ int buf[128];
    int t = threadIdx.x;
    int v = (t < 98) ? btot[t] : 0;
    buf[t] = v;
    __syncthreads();
    for (int d = 1; d < 128; d <<= 1) {
        int add = (t >= d) ? buf[t - d] : 0;
        __syncthreads();
        buf[t] += add;
        __syncthreads();
    }
    if (t < 98) btot2[t] = buf[t] - v;
}

__global__ void scatter_kernel(const int* __restrict__ idx, const int* __restrict__ flag,
                               int* __restrict__ offs, const int* __restrict__ btot2,
                               unsigned* __restrict__ sedge) {
    int e = blockIdx.x * blockDim.x + threadIdx.x;
    int src, dst;
    if (*flag) { src = idx[e];     dst = idx[NE + e]; }
    else       { src = idx[2 * e]; dst = idx[2 * NE + 2 * e]; }
    int pos = atomicAdd(&offs[dst], 1) + btot2[dst >> 9];
    sedge[pos] = ((unsigned)dst << 16) | (unsigned)src;
}

// --- MFMA edge kernel v5: 32-edge batches (8 KB LDS/wave) + waves_per_eu(4,4)
//     -> 4 blocks/CU, 4 waves/SIMD. Fits the 128-VGPR budget by NOT keeping W2
//     fragments register-resident: B-frags re-read per batch from global
//     (W2TH/W2TL are 8 KB, L1-resident), nt-outer / mt-inner MFMA loop.
//     Staging / Dt / segmented-max logic identical to the verified 32-edge
//     version. Gather latency hidden by 4 waves/SIMD. ---
__global__ __attribute__((amdgpu_flat_work_group_size(256, 256), amdgpu_waves_per_eu(4, 4)))
void edge_kernel(
    const unsigned* __restrict__ sedge,
    const float* __restrict__ U, const float* __restrict__ V,
    const unsigned short* __restrict__ W2TH, const unsigned short* __restrict__ W2TL,
    const float* __restrict__ b2, float* __restrict__ out) {
    __shared__ char smem[32768];                 // 4 waves x 8 KB, wave-private
    int lane = threadIdx.x & 63;
    int wib  = threadIdx.x >> 6;
    char* base = smem + wib * 8192;              // Hhi [0,4K) Hlo [4K,8K); Dt overlays 8K
    char* Hhi = base;
    char* Hlo = base + 4096;
    int l15 = lane & 15, l4 = lane >> 4;

    float bias = b2[lane];                       // lane = output column

    // XCD-chunked swizzle: 1024 blocks, 8 XCDs -> contiguous 128-block chunks per XCD
    int bid = blockIdx.x;
    int swz = (bid & 7) * 128 + (bid >> 3);
    int wid = swz * 4 + wib;                     // 4096 waves
    const int NB = NE / 32;                      // 25000 batches
    int bstart = (int)(((long long)wid * NB) >> 12);
    int bend   = (int)(((long long)(wid + 1) * NB) >> 12);
    if (bstart >= bend) return;

    int myrow = lane >> 1;                       // edge row this lane loads
    int hf    = lane & 1;                        // which half of the 64-f row

    float run = -3.402823e38f;
    int   segdst = -1;
    bool  firstflush = true;

    unsigned pe = sedge[bstart * 32 + myrow];

    for (int b = bstart; b < bend; ++b) {
        unsigned pec = pe;
        if (b + 1 < bend) pe = sedge[(b + 1) * 32 + myrow];   // prefetch next batch
        int src = (int)(pec & 0xffffu);
        int dst = (int)(pec >> 16);

        // ---- staging: relu(U[dst]+V[src]) -> bf16 hi/lo into LDS (lane pair/row)
        const float4* Ur = (const float4*)(U + (size_t)dst * F) + hf * 8;
        const float4* Vr = (const float4*)(V + (size_t)src * F) + hf * 8;
#pragma unroll
        for (int cc = 0; cc < 4; ++cc) {
            float4 ua = Ur[2 * cc], ub = Ur[2 * cc + 1];
            float4 va = Vr[2 * cc], vb = Vr[2 * cc + 1];
            float f[8] = {ua.x + va.x, ua.y + va.y, ua.z + va.z, ua.w + va.w,
                          ub.x + vb.x, ub.y + vb.y, ub.z + vb.z, ub.w + vb.w};
            unsigned hi[4], lo[4];
#pragma unroll
            for (int p = 0; p < 4; ++p) {
                float f0 = relu_f(f[2 * p]), f1 = relu_f(f[2 * p + 1]);
                unsigned u0 = __float_as_uint(f0), u1 = __float_as_uint(f1);
                unsigned h0 = u0 & 0xffff0000u, h1 = u1 & 0xffff0000u;
                float l0 = f0 - __uint_as_float(h0);
                float l1 = f1 - __uint_as_float(h1);
                hi[p] = h1 | (h0 >> 16);
                lo[p] = (__float_as_uint(l1) & 0xffff0000u) | (__float_as_uint(l0) >> 16);
            }
            int g = hf * 4 + cc;                 // 16B granule index within row (k slice)
            int byt = myrow * 128 + ((g ^ (myrow & 7)) << 4);
            *(uint4*)(Hhi + byt) = make_uint4(hi[0], hi[1], hi[2], hi[3]);
            *(uint4*)(Hlo + byt) = make_uint4(lo[0], lo[1], lo[2], lo[3]);
        }

        int pdst = __shfl_up(dst, 2, 64);        // row r-1's dst
        bool leader = (lane < 2) || (pdst != dst);
        unsigned long long lead_mask = __ballot(leader);
        int dst0 = __shfl(dst, 0, 64);

        // ---- MFMA: nt-outer (B-frags transient from global/L1), mt-inner (A from LDS)
        f32x4 acc[2][4];
#pragma unroll
        for (int mt = 0; mt < 2; ++mt)
#pragma unroll
            for (int nt = 0; nt < 4; ++nt)
                acc[mt][nt] = (f32x4){0.f, 0.f, 0.f, 0.f};
#pragma unroll
        for (int nt = 0; nt < 4; ++nt) {
            int boff = (nt * 16 + l15) * 64 + l4 * 8;
            bf16x8 Bh0 = *(const bf16x8*)(W2TH + boff);
            bf16x8 Bh1 = *(const bf16x8*)(W2TH + boff + 32);
            bf16x8 Bl0 = *(const bf16x8*)(W2TL + boff);
            bf16x8 Bl1 = *(const bf16x8*)(W2TL + boff + 32);
#pragma unroll
            for (int mt = 0; mt < 2; ++mt) {
                int arow = mt * 16 + l15;
                int abase = arow * 128;
                int am = arow & 7;
                bf16x8 Ah0 = *(const bf16x8*)(Hhi + abase + (((0 + l4) ^ am) << 4));
                bf16x8 Ah1 = *(const bf16x8*)(Hhi + abase + (((4 + l4) ^ am) << 4));
                bf16x8 Al0 = *(const bf16x8*)(Hlo + abase + (((0 + l4) ^ am) << 4));
                bf16x8 Al1 = *(const bf16x8*)(Hlo + abase + (((4 + l4) ^ am) << 4));
                f32x4 a = acc[mt][nt];
                a = __builtin_amdgcn_mfma_f32_16x16x32_bf16(Ah0, Bh0, a, 0, 0, 0);
                a = __builtin_amdgcn_mfma_f32_16x16x32_bf16(Ah1, Bh1, a, 0, 0, 0);
                a = __builtin_amdgcn_mfma_f32_16x16x32_bf16(Al0, Bh0, a, 0, 0, 0);
                a = __builtin_amdgcn_mfma_f32_16x16x32_bf16(Al1, Bh1, a, 0, 0, 0);
                a = __builtin_amdgcn_mfma_f32_16x16x32_bf16(Ah0, Bl0, a, 0, 0, 0);
                a = __builtin_amdgcn_mfma_f32_16x16x32_bf16(Ah1, Bl1, a, 0, 0, 0);
                acc[mt][nt] = a;
            }
        }

        // ---- store D transposed: Dt[col][row] (64 cols x 32 rows), col-granule swizzle
#pragma unroll
        for (int mt = 0; mt < 2; ++mt)
#pragma unroll
            for (int nt = 0; nt < 4; ++nt) {
                int col = nt * 16 + l15;
                int gst = mt * 4 + l4;           // 0..7 -> rows gst*4..+4
                *(f32x4*)(base + col * 128 + ((gst ^ (col & 7)) << 4)) = acc[mt][nt];
            }

        // ---- lane c streams column c (32 rows) with cross-batch carry
#pragma unroll
        for (int g = 0; g < 8; ++g) {
            float4 dv = *(const float4*)(base + lane * 128 + ((g ^ (lane & 7)) << 4));
            float vals[4] = {dv.x, dv.y, dv.z, dv.w};
#pragma unroll
            for (int r = 0; r < 4; ++r) {
                int row = 4 * g + r;
                bool newseg;
                int nd;
                if (row == 0) { newseg = (dst0 != segdst); nd = dst0; }
                else {
                    newseg = ((lead_mask >> (2 * row)) & 1ull) != 0ull;
                    nd = newseg ? __shfl(dst, 2 * row, 64) : 0;
                }
                if (newseg) {                                  // wave-uniform branch
                    if (segdst >= 0) {
                        float val = fmaxf(run + bias, 0.f);
                        if (firstflush) {                      // may extend into prev range
                            if (val > 0.f)
                                atomicMax((int*)(out + (size_t)segdst * F + lane),
                                          __float_as_int(val));
                            firstflush = false;
                        } else {                               // sole writer
                            out[(size_t)segdst * F + lane] = val;
                        }
                    }
                    run = -3.402823e38f;
                    segdst = nd;
                }
                run = fmaxf(run, vals[r]);
            }
        }
    }
    if (segdst >= 0) {   // final segment may extend into next range -> atomic
        float val = fmaxf(run + bias, 0.f);
        if (val > 0.f)
            atomicMax((int*)(out + (size_t)segdst * F + lane), __float_as_int(val));
    }
}

extern "C" void kernel_launch(void* const* d_in, const int* in_sizes, int n_in,
                              void* d_out, int out_size, void* d_ws, size_t ws_size,
                              hipStream_t stream) {
    const float* x  = (const float*)d_in[0];
    const int*   ei = (const int*)d_in[1];
    const float* W1 = (const float*)d_in[2];
    const float* b1 = (const float*)d_in[3];
    const float* W2 = (const float*)d_in[4];
    const float* b2 = (const float*)d_in[5];
    float* out = (float*)d_out;

    char* ws = (char*)d_ws;
    int*            flag  = (int*)(ws + WS_FLAG);
    unsigned short* WCTH  = (unsigned short*)(ws + WS_WCTH);
    unsigned short* WCTL  = (unsigned short*)(ws + WS_WCTL);
    unsigned short* W2TH  = (unsigned short*)(ws + WS_W2TH);
    unsigned short* W2TL  = (unsigned short*)(ws + WS_W2TL);
    unsigned*       sedge = (unsigned*)(ws + WS_SEDGE);
    float*          Ubuf  = (float*)(ws + WS_U);
    float*          Vbuf  = (float*)(ws + WS_V);
    int*            bins  = (int*)(ws + WS_BINS);
    int*            offs  = (int*)(ws + WS_OFFS);
    int*            btot  = (int*)(ws + WS_BTOT);
    int*            btot2 = (int*)(ws + WS_BTOT2);

    hipMemsetAsync(flag, 0, 4, stream);
    hipMemsetAsync(bins, 0, (size_t)NN * 4, stream);
    detect_kernel<<<16, 256, 0, stream>>>(ei, flag);
    prep_kernel<<<48, 256, 0, stream>>>(W1, W2, WCTH, WCTL, W2TH, W2TL);
    hist_kernel<<<NE / 256, 256, 0, stream>>>(ei, flag, bins);
    scanA_kernel<<<98, 512, 0, stream>>>(bins, offs, btot);
    scanB_kernel<<<1, 128, 0, stream>>>(btot, btot2);
    scatter_kernel<<<NE / 256, 256, 0, stream>>>(ei, flag, offs, btot2, sedge);

    const float* xin = x;
    for (int l = 0; l < 3; ++l) {
        gemm_mfma<<<391, 256, 0, stream>>>(xin, WCTH + l * 8192, WCTL + l * 8192,
                                           b1 + l * 64, Ubuf, Vbuf);
        hipMemsetAsync(out, 0, (size_t)NN * F * sizeof(float), stream);
        edge_kernel<<<1024, 256, 0, stream>>>(sedge, Ubuf, Vbuf,
                                              W2TH + l * 4096, W2TL + l * 4096,
                                              b2 + l * 64, out);
        xin = out;
    }
}

// Round 5
// 414.964 us; speedup vs baseline: 1.2198x; 1.2198x over previous
//
#include <hip/hip_runtime.h>

#define NN 50000
#define NE 800000
#define F  64

typedef __attribute__((ext_vector_type(8))) short bf16x8;
typedef __attribute__((ext_vector_type(4))) float f32x4;

// ---- workspace layout (bytes), 256-aligned ----
#define WS_FLAG   0u
#define WS_WCTH   256u        // 3*128*64 u16: [A|B]^T hi    -> 49408
#define WS_WCTL   49408u      // 3*128*64 u16: [A|B]^T lo    -> 98560
#define WS_W2TH   98560u      // 3*4096 u16 (bf16 hi of W2T) -> 123136
#define WS_W2TL   123136u     // 3*4096 u16 (bf16 lo of W2T) -> 147712
#define WS_SEDGE  147712u     // NE u32 packed (dst<<16)|src -> 3347712
#define WS_U      3347712u    // NN*F f32                    -> 16147712
#define WS_V      16147712u   // NN*F f32                    -> 28947712
// sort scratch aliased inside U region (sort completes before first gemm writes U)
#define WS_BINS   (WS_U + 0u)        // NN int
#define WS_OFFS   (WS_U + 204800u)   // NN int
#define WS_BTOT   (WS_U + 409600u)   // 98 int
#define WS_BTOT2  (WS_U + 410112u)   // 98 int

__device__ __forceinline__ float relu_f(float a) { return a > 0.f ? a : 0.f; }

// --- detect idx payload: int64 (odd words all zero) vs int32 ---
__global__ void detect_kernel(const int* __restrict__ idx, int* __restrict__ flag) {
    int t = blockIdx.x * blockDim.x + threadIdx.x;   // 4096 samples
    if (idx[2 * t + 1] != 0) atomicOr(flag, 1);      // 1 -> int32 layout
}

// --- build transposed hi/lo bf16 splits: WC = [A|B] (A = W1a - W1b, B = W1b), W2T ---
__global__ void prep_kernel(const float* __restrict__ W1, const float* __restrict__ W2,
                            unsigned short* __restrict__ WCTH, unsigned short* __restrict__ WCTL,
                            unsigned short* __restrict__ W2TH, unsigned short* __restrict__ W2TL) {
    int i = blockIdx.x * blockDim.x + threadIdx.x;   // 0 .. 3*4096-1
    int l = i >> 12;
    int r = i & 4095;
    int k = r >> 6;
    int j = r & 63;
    float wa = W1[l * 8192 + k * 64 + j];
    float wb = W1[l * 8192 + 4096 + k * 64 + j];
    float a = wa - wb;
    unsigned ua = __float_as_uint(a), ahi = ua & 0xffff0000u;
    float alo = a - __uint_as_float(ahi);
    WCTH[l * 8192 + j * 64 + k] = (unsigned short)(ahi >> 16);
    WCTL[l * 8192 + j * 64 + k] = (unsigned short)(__float_as_uint(alo) >> 16);
    unsigned ub = __float_as_uint(wb), bhi = ub & 0xffff0000u;
    float blo = wb - __uint_as_float(bhi);
    WCTH[l * 8192 + (64 + j) * 64 + k] = (unsigned short)(bhi >> 16);
    WCTL[l * 8192 + (64 + j) * 64 + k] = (unsigned short)(__float_as_uint(blo) >> 16);
    float w = W2[l * 4096 + k * 64 + j];
    unsigned uw = __float_as_uint(w), whi = uw & 0xffff0000u;
    float wlo = w - __uint_as_float(whi);
    W2TH[l * 4096 + j * 64 + k] = (unsigned short)(whi >> 16);
    W2TL[l * 4096 + j * 64 + k] = (unsigned short)(__float_as_uint(wlo) >> 16);
}

// --- MFMA gemm: [U|V] = x @ [A|B] (+b1 on U). Wave = (64-node batch) x (U or V half). ---
__global__ __attribute__((amdgpu_flat_work_group_size(256, 256), amdgpu_waves_per_eu(2, 2)))
void gemm_mfma(
    const float* __restrict__ xin,
    const unsigned short* __restrict__ WCTH, const unsigned short* __restrict__ WCTL,
    const float* __restrict__ b1,
    float* __restrict__ U, float* __restrict__ V) {
    __shared__ char smem[65536];                 // 4 waves x 16 KB, wave-private
    int lane = threadIdx.x & 63;
    int wib  = threadIdx.x >> 6;
    char* base = smem + wib * 16384;
    char* Hhi = base;
    char* Hlo = base + 8192;
    int l15 = lane & 15, l4 = lane >> 4;

    int wid = blockIdx.x * 4 + wib;              // 1564 waves exactly
    int b = wid >> 1;                            // node batch (0..781)
    int half = wid & 1;                          // 0 -> U, 1 -> V

    bf16x8 Bh[2][4], Bl[2][4];
#pragma unroll
    for (int kt = 0; kt < 2; ++kt)
#pragma unroll
        for (int nt = 0; nt < 4; ++nt) {
            int off = (half * 64 + nt * 16 + l15) * 64 + kt * 32 + l4 * 8;
            Bh[kt][nt] = *(const bf16x8*)(WCTH + off);
            Bl[kt][nt] = *(const bf16x8*)(WCTL + off);
        }

    int node = b * 64 + lane;
    int cnode = node < NN ? node : NN - 1;
    const float4* xr = (const float4*)(xin + (size_t)cnode * F);
#pragma unroll
    for (int cc = 0; cc < 8; ++cc) {
        float4 xa = xr[2 * cc], xb = xr[2 * cc + 1];
        float f[8] = {xa.x, xa.y, xa.z, xa.w, xb.x, xb.y, xb.z, xb.w};
        unsigned hi[4], lo[4];
#pragma unroll
        for (int p = 0; p < 4; ++p) {
            float f0 = f[2 * p], f1 = f[2 * p + 1];
            unsigned u0 = __float_as_uint(f0), u1 = __float_as_uint(f1);
            unsigned h0 = u0 & 0xffff0000u, h1 = u1 & 0xffff0000u;
            float l0 = f0 - __uint_as_float(h0);
            float l1 = f1 - __uint_as_float(h1);
            hi[p] = h1 | (h0 >> 16);
            lo[p] = (__float_as_uint(l1) & 0xffff0000u) | (__float_as_uint(l0) >> 16);
        }
        int byt = lane * 128 + ((cc ^ (lane & 7)) << 4);
        *(uint4*)(Hhi + byt) = make_uint4(hi[0], hi[1], hi[2], hi[3]);
        *(uint4*)(Hlo + byt) = make_uint4(lo[0], lo[1], lo[2], lo[3]);
    }

    f32x4 acc[4][4];
#pragma unroll
    for (int mt = 0; mt < 4; ++mt)
#pragma unroll
        for (int nt = 0; nt < 4; ++nt)
            acc[mt][nt] = (f32x4){0.f, 0.f, 0.f, 0.f};
#pragma unroll
    for (int mt = 0; mt < 4; ++mt) {
        int arow = mt * 16 + l15;
        int abase = arow * 128;
        int am = arow & 7;
        bf16x8 Ah0 = *(const bf16x8*)(Hhi + abase + (((0 + l4) ^ am) << 4));
        bf16x8 Ah1 = *(const bf16x8*)(Hhi + abase + (((4 + l4) ^ am) << 4));
        bf16x8 Al0 = *(const bf16x8*)(Hlo + abase + (((0 + l4) ^ am) << 4));
        bf16x8 Al1 = *(const bf16x8*)(Hlo + abase + (((4 + l4) ^ am) << 4));
#pragma unroll
        for (int nt = 0; nt < 4; ++nt) {
            f32x4 a = acc[mt][nt];
            a = __builtin_amdgcn_mfma_f32_16x16x32_bf16(Ah0, Bh[0][nt], a, 0, 0, 0);
            a = __builtin_amdgcn_mfma_f32_16x16x32_bf16(Ah1, Bh[1][nt], a, 0, 0, 0);
            a = __builtin_amdgcn_mfma_f32_16x16x32_bf16(Al0, Bh[0][nt], a, 0, 0, 0);
            a = __builtin_amdgcn_mfma_f32_16x16x32_bf16(Al1, Bh[1][nt], a, 0, 0, 0);
            a = __builtin_amdgcn_mfma_f32_16x16x32_bf16(Ah0, Bl[0][nt], a, 0, 0, 0);
            a = __builtin_amdgcn_mfma_f32_16x16x32_bf16(Ah1, Bl[1][nt], a, 0, 0, 0);
            acc[mt][nt] = a;
        }
    }

    float bc[4];
#pragma unroll
    for (int nt = 0; nt < 4; ++nt)
        bc[nt] = (half == 0) ? b1[nt * 16 + l15] : 0.f;
    float* outp = (half == 0) ? U : V;
#pragma unroll
    for (int mt = 0; mt < 4; ++mt)
#pragma unroll
        for (int nt = 0; nt < 4; ++nt) {
            int col = nt * 16 + l15;
#pragma unroll
            for (int r = 0; r < 4; ++r) {
                int row = b * 64 + mt * 16 + l4 * 4 + r;
                if (row < NN) outp[(size_t)row * F + col] = acc[mt][nt][r] + bc[nt];
            }
        }
}

// --- counting sort by dst ---
__global__ void hist_kernel(const int* __restrict__ idx, const int* __restrict__ flag,
                            int* __restrict__ bins) {
    int e = blockIdx.x * blockDim.x + threadIdx.x;
    int dst = (*flag) ? idx[NE + e] : idx[2 * NE + 2 * e];
    atomicAdd(&bins[dst], 1);
}

__global__ __launch_bounds__(512) void scanA_kernel(const int* __restrict__ bins,
                                                    int* __restrict__ offs,
                                                    int* __restrict__ btot) {
    __shared__ int buf[512];
    int t = threadIdx.x;
    int i = blockIdx.x * 512 + t;
    int v = (i < NN) ? bins[i] : 0;
    buf[t] = v;
    __syncthreads();
    for (int d = 1; d < 512; d <<= 1) {
        int add = (t >= d) ? buf[t - d] : 0;
        __syncthreads();
        buf[t] += add;
        __syncthreads();
    }
    if (i < NN) offs[i] = buf[t] - v;
    if (t == 511) btot[blockIdx.x] = buf[511];
}

__global__ __launch_bounds__(128) void scanB_kernel(const int* __restrict__ btot,
                                                    int* __restrict__ btot2) {
    __shared__ int buf[128];
    int t = threadIdx.x;
    int v = (t < 98) ? btot[t] : 0;
    buf[t] = v;
    __syncthreads();
    for (int d = 1; d < 128; d <<= 1) {
        int add = (t >= d) ? buf[t - d] : 0;
        __syncthreads();
        buf[t] += add;
        __syncthreads();
    }
    if (t < 98) btot2[t] = buf[t] - v;
}

__global__ void scatter_kernel(const int* __restrict__ idx, const int* __restrict__ flag,
                               int* __restrict__ offs, const int* __restrict__ btot2,
                               unsigned* __restrict__ sedge) {
    int e = blockIdx.x * blockDim.x + threadIdx.x;
    int src, dst;
    if (*flag) { src = idx[e];     dst = idx[NE + e]; }
    else       { src = idx[2 * e]; dst = idx[2 * NE + 2 * e]; }
    int pos = atomicAdd(&offs[dst], 1) + btot2[dst >> 9];
    sedge[pos] = ((unsigned)dst << 16) | (unsigned)src;
}

// --- MFMA edge kernel v6: v1 geometry (64-edge batches, 16 KB LDS/wave, 2 waves/SIMD)
//     with the register file re-timed for memory-level parallelism:
//     * staging loads issued 16-at-a-time into uu[8]/vv[8] arrays (2 halves)
//       -> 2 latency exposures per batch instead of ~8
//     * W2 fragments NOT register-resident across staging: re-loaded per batch
//       from global (L1/L2-hot, 16 KB) through a laundered pointer so LICM
//       cannot hoist them back out of the loop.
//     MFMA / Dt transpose / segmented-max logic identical to the verified v1. ---
__global__ __attribute__((amdgpu_flat_work_group_size(256, 256), amdgpu_waves_per_eu(2, 2)))
void edge_kernel(
    const unsigned* __restrict__ sedge,
    const float* __restrict__ U, const float* __restrict__ V,
    const unsigned short* __restrict__ W2TH, const unsigned short* __restrict__ W2TL,
    const float* __restrict__ b2, float* __restrict__ out) {
    __shared__ char smem[65536];                 // 4 waves x 16 KB, wave-private
    int lane = threadIdx.x & 63;
    int wib  = threadIdx.x >> 6;
    char* base = smem + wib * 16384;             // Hhi [0,8K) Hlo [8K,16K); Dt overlays
    char* Hhi = base;
    char* Hlo = base + 8192;
    int l15 = lane & 15, l4 = lane >> 4;

    float bias = b2[lane];                       // lane = output column

    // XCD-chunked swizzle: 512 blocks, 8 XCDs -> contiguous 64-block chunks per XCD
    int bid = blockIdx.x;
    int swz = (bid & 7) * 64 + (bid >> 3);
    int wid = swz * 4 + wib;                     // 2048 waves
    const int NB = NE / 64;                      // 12500 batches
    int bstart = (int)(((long long)wid * NB) >> 11);
    int bend   = (int)(((long long)(wid + 1) * NB) >> 11);

    float run = -3.402823e38f;
    int   segdst = -1;
    bool  firstflush = true;

    unsigned pe = sedge[bstart * 64 + lane];

    for (int b = bstart; b < bend; ++b) {
        int src = (int)(pe & 0xffffu);
        int dst = (int)(pe >> 16);

        // ---- staging: two halves; each half issues 16 independent loads, then
        //      converts relu(U+V) to bf16 hi/lo and writes LDS
        const float4* Ur = (const float4*)(U + (size_t)dst * F);
        const float4* Vr = (const float4*)(V + (size_t)src * F);
#pragma unroll
        for (int h = 0; h < 2; ++h) {
            float4 uu[8], vv[8];
#pragma unroll
            for (int q = 0; q < 8; ++q) uu[q] = Ur[8 * h + q];
#pragma unroll
            for (int q = 0; q < 8; ++q) vv[q] = Vr[8 * h + q];
#pragma unroll
            for (int cc = 0; cc < 4; ++cc) {
                float4 ua = uu[2 * cc], ub = uu[2 * cc + 1];
                float4 va = vv[2 * cc], vb = vv[2 * cc + 1];
                float f[8] = {ua.x + va.x, ua.y + va.y, ua.z + va.z, ua.w + va.w,
                              ub.x + vb.x, ub.y + vb.y, ub.z + vb.z, ub.w + vb.w};
                unsigned hi[4], lo[4];
#pragma unroll
                for (int p = 0; p < 4; ++p) {
                    float f0 = relu_f(f[2 * p]), f1 = relu_f(f[2 * p + 1]);
                    unsigned u0 = __float_as_uint(f0), u1 = __float_as_uint(f1);
                    unsigned h0 = u0 & 0xffff0000u, h1 = u1 & 0xffff0000u;
                    float l0 = f0 - __uint_as_float(h0);
                    float l1 = f1 - __uint_as_float(h1);
                    hi[p] = h1 | (h0 >> 16);
                    lo[p] = (__float_as_uint(l1) & 0xffff0000u) | (__float_as_uint(l0) >> 16);
                }
                int g = 4 * h + cc;              // 16B granule index within row
                int byt = lane * 128 + ((g ^ (lane & 7)) << 4);
                *(uint4*)(Hhi + byt) = make_uint4(hi[0], hi[1], hi[2], hi[3]);
                *(uint4*)(Hlo + byt) = make_uint4(lo[0], lo[1], lo[2], lo[3]);
            }
        }

        // next-batch edge word: issue early, consumed at loop bottom
        unsigned pe_n = (b + 1 < bend) ? sedge[(b + 1) * 64 + lane] : 0u;

        int pdst = __shfl_up(dst, 1, 64);
        bool leader = (lane == 0) || (pdst != dst);
        unsigned long long lead_mask = __ballot(leader);
        int dst0 = __shfl(dst, 0, 64);

        // ---- W2 fragments: re-load per batch from L1/L2 (laundered pointers so
        //      the loads stay inside the loop; staging regs are dead by now)
        const unsigned short* w2h = W2TH;
        const unsigned short* w2l = W2TL;
        asm volatile("" : "+s"(w2h), "+s"(w2l));
        bf16x8 Bh[2][4], Bl[2][4];
#pragma unroll
        for (int kt = 0; kt < 2; ++kt)
#pragma unroll
            for (int nt = 0; nt < 4; ++nt) {
                int off = (nt * 16 + l15) * 64 + kt * 32 + l4 * 8;
                Bh[kt][nt] = *(const bf16x8*)(w2h + off);
                Bl[kt][nt] = *(const bf16x8*)(w2l + off);
            }

        // ---- MFMA (v1 exact)
        f32x4 acc[4][4];
#pragma unroll
        for (int mt = 0; mt < 4; ++mt)
#pragma unroll
            for (int nt = 0; nt < 4; ++nt)
                acc[mt][nt] = (f32x4){0.f, 0.f, 0.f, 0.f};
#pragma unroll
        for (int mt = 0; mt < 4; ++mt) {
            int arow = mt * 16 + l15;
            int abase = arow * 128;
            int am = arow & 7;
            bf16x8 Ah0 = *(const bf16x8*)(Hhi + abase + (((0 + l4) ^ am) << 4));
            bf16x8 Ah1 = *(const bf16x8*)(Hhi + abase + (((4 + l4) ^ am) << 4));
            bf16x8 Al0 = *(const bf16x8*)(Hlo + abase + (((0 + l4) ^ am) << 4));
            bf16x8 Al1 = *(const bf16x8*)(Hlo + abase + (((4 + l4) ^ am) << 4));
#pragma unroll
            for (int nt = 0; nt < 4; ++nt) {
                f32x4 a = acc[mt][nt];
                a = __builtin_amdgcn_mfma_f32_16x16x32_bf16(Ah0, Bh[0][nt], a, 0, 0, 0);
                a = __builtin_amdgcn_mfma_f32_16x16x32_bf16(Ah1, Bh[1][nt], a, 0, 0, 0);
                a = __builtin_amdgcn_mfma_f32_16x16x32_bf16(Al0, Bh[0][nt], a, 0, 0, 0);
                a = __builtin_amdgcn_mfma_f32_16x16x32_bf16(Al1, Bh[1][nt], a, 0, 0, 0);
                a = __builtin_amdgcn_mfma_f32_16x16x32_bf16(Ah0, Bl[0][nt], a, 0, 0, 0);
                a = __builtin_amdgcn_mfma_f32_16x16x32_bf16(Ah1, Bl[1][nt], a, 0, 0, 0);
                acc[mt][nt] = a;
            }
        }

        // ---- store D transposed (Dt[col][row], col-granule swizzle), then
        //      lane c streams column c with cross-batch carry
#pragma unroll
        for (int mt = 0; mt < 4; ++mt)
#pragma unroll
            for (int nt = 0; nt < 4; ++nt) {
                int col = nt * 16 + l15;
                int gst = mt * 4 + l4;
                *(f32x4*)(base + col * 256 + ((gst ^ (col & 15)) << 4)) = acc[mt][nt];
            }

#pragma unroll
        for (int g = 0; g < 16; ++g) {
            float4 dv = *(const float4*)(base + lane * 256 + ((g ^ (lane & 15)) << 4));
            float vals[4] = {dv.x, dv.y, dv.z, dv.w};
#pragma unroll
            for (int r = 0; r < 4; ++r) {
                int row = 4 * g + r;
                bool newseg;
                int nd;
                if (row == 0) { newseg = (dst0 != segdst); nd = dst0; }
                else {
                    newseg = ((lead_mask >> row) & 1ull) != 0ull;
                    nd = newseg ? __shfl(dst, row, 64) : 0;
                }
                if (newseg) {                                  // wave-uniform branch
                    if (segdst >= 0) {
                        float val = fmaxf(run + bias, 0.f);
                        if (firstflush) {                      // may extend into prev range
                            if (val > 0.f)
                                atomicMax((int*)(out + (size_t)segdst * F + lane),
                                          __float_as_int(val));
                            firstflush = false;
                        } else {                               // sole writer
                            out[(size_t)segdst * F + lane] = val;
                        }
                    }
                    run = -3.402823e38f;
                    segdst = nd;
                }
                run = fmaxf(run, vals[r]);
            }
        }

        pe = pe_n;
    }
    if (segdst >= 0) {   // final segment may extend into next range -> atomic
        float val = fmaxf(run + bias, 0.f);
        if (val > 0.f)
            atomicMax((int*)(out + (size_t)segdst * F + lane), __float_as_int(val));
    }
}

extern "C" void kernel_launch(void* const* d_in, const int* in_sizes, int n_in,
                              void* d_out, int out_size, void* d_ws, size_t ws_size,
                              hipStream_t stream) {
    const float* x  = (const float*)d_in[0];
    const int*   ei = (const int*)d_in[1];
    const float* W1 = (const float*)d_in[2];
    const float* b1 = (const float*)d_in[3];
    const float* W2 = (const float*)d_in[4];
    const float* b2 = (const float*)d_in[5];
    float* out = (float*)d_out;

    char* ws = (char*)d_ws;
    int*            flag  = (int*)(ws + WS_FLAG);
    unsigned short* WCTH  = (unsigned short*)(ws + WS_WCTH);
    unsigned short* WCTL  = (unsigned short*)(ws + WS_WCTL);
    unsigned short* W2TH  = (unsigned short*)(ws + WS_W2TH);
    unsigned short* W2TL  = (unsigned short*)(ws + WS_W2TL);
    unsigned*       sedge = (unsigned*)(ws + WS_SEDGE);
    float*          Ubuf  = (float*)(ws + WS_U);
    float*          Vbuf  = (float*)(ws + WS_V);
    int*            bins  = (int*)(ws + WS_BINS);
    int*            offs  = (int*)(ws + WS_OFFS);
    int*            btot  = (int*)(ws + WS_BTOT);
    int*            btot2 = (int*)(ws + WS_BTOT2);

    hipMemsetAsync(flag, 0, 4, stream);
    hipMemsetAsync(bins, 0, (size_t)NN * 4, stream);
    detect_kernel<<<16, 256, 0, stream>>>(ei, flag);
    prep_kernel<<<48, 256, 0, stream>>>(W1, W2, WCTH, WCTL, W2TH, W2TL);
    hist_kernel<<<NE / 256, 256, 0, stream>>>(ei, flag, bins);
    scanA_kernel<<<98, 512, 0, stream>>>(bins, offs, btot);
    scanB_kernel<<<1, 128, 0, stream>>>(btot, btot2);
    scatter_kernel<<<NE / 256, 256, 0, stream>>>(ei, flag, offs, btot2, sedge);

    const float* xin = x;
    for (int l = 0; l < 3; ++l) {
        gemm_mfma<<<391, 256, 0, stream>>>(xin, WCTH + l * 8192, WCTL + l * 8192,
                                           b1 + l * 64, Ubuf, Vbuf);
        hipMemsetAsync(out, 0, (size_t)NN * F * sizeof(float), stream);
        edge_kernel<<<512, 256, 0, stream>>>(sedge, Ubuf, Vbuf,
                                             W2TH + l * 4096, W2TL + l * 4096,
                                             b2 + l * 64, out);
        xin = out;
    }
}